// Round 14
// baseline (59.719 us; speedup 1.0000x reference)
//
#include <hip/hip_runtime.h>
#include <hip/hip_bf16.h>

// Problem constants
#define BATCH   4096
#define NF      128    // n features == n models
#define NA      16
#define IN_DIM  144    // K = 144 exactly (9 MFMA k-steps of 16; 18 8-elem chunks)
#define KP      144    // w1t K (b1 folded via MFMA C-operand)
#define NKC     18     // fab2 k-chunks
#define HID     256

typedef __attribute__((ext_vector_type(8))) short bf16x8;
typedef __attribute__((ext_vector_type(4))) float f32x4;
typedef __attribute__((ext_vector_type(16))) float f32x16;

// ---------------------------------------------------------------------------
// Merged convert kernel:
//   blocks [0, 1152):      W1 [128][144][256] fp32 -> w1t [128][256][144] bf16
//                          (transposed; b1 folded later via MFMA C-operand)
//   blocks [1152, 1440):   fa -> fab2 bf16, K-CHUNK-MAJOR [18][4096][8]:
//                          plane kc holds k = kc*8..kc*8+8 for all rows ->
//                          a half-wave's frag load is 512 B contiguous.
__global__ void convert_all(const float* __restrict__ W1,
                            const float* __restrict__ f_t,
                            const float* __restrict__ a_t,
                            __hip_bfloat16* __restrict__ w1t,
                            __hip_bfloat16* __restrict__ fab2) {
    const int bid = blockIdx.x;
    const int t = threadIdx.x;
    if (bid < 1152) {
        __shared__ float tile[16][HID];
        int m = bid / 9;
        int kc = bid - m * 9;
        int k0 = kc * 16;
#pragma unroll
        for (int i = 0; i < 16; ++i)
            tile[i][t] = W1[((size_t)m * IN_DIM + (k0 + i)) * HID + t];
        __syncthreads();
        union { ushort us[16]; uint4 q[2]; } pk;
#pragma unroll
        for (int i = 0; i < 16; ++i) {
            __hip_bfloat16 h = __float2bfloat16(tile[i][t]);
            pk.us[i] = *(ushort*)&h;
        }
        uint4* dst = (uint4*)(w1t + ((size_t)m * HID + t) * KP + k0);
        dst[0] = pk.q[0];
        dst[1] = pk.q[1];
    } else {
        int b2i = bid - 1152;          // 0..287
        int cc = b2i / 16;             // k-chunk 0..17
        int rb = b2i - cc * 16;        // row block 0..15
        int row = rb * 256 + t;
        union { ushort us[8]; uint4 q; } pk;
        const float* src = (cc < 16) ? (f_t + (size_t)row * NF + cc * 8)
                                     : (a_t + (size_t)row * NA + (cc - 16) * 8);
#pragma unroll
        for (int j = 0; j < 8; ++j) {
            __hip_bfloat16 h = __float2bfloat16(src[j]);
            pk.us[j] = *(ushort*)&h;
        }
        *(uint4*)(fab2 + ((size_t)cc * BATCH + row) * 8) = pk.q;   // coalesced
    }
}

// ---------------------------------------------------------------------------
// Fused grouped MLP — barrier-free main loop, operands never touch LDS.
// Grid 512 = 128 m (bid&127) x 4 slices of 1024 rows; 16 tiles of 64 rows.
// 256 thr = 4 waves; wave w owns hid cols [w*64, w*64+64) = 2 x 32-tiles.
// B (W1T[m]) in registers (loaded once). A-frags loaded straight from the
// k-chunk-major fab2 (each half-wave = 512 B contiguous; 18 KB/tile, L1-hits
// for 3 of 4 waves). Per-tile results go to partial[16][4][64] (LDS, no
// sync); ONE barrier at the end, then the combine. 8 independent wave
// streams per CU -> MFMA/VALU/vmem pipes overlap instead of lockstepping.
// mfma(A=w1t frag, B=fa frag): D[row=hid][col=batch].
//  A/B frag (32x32x16): lane holds row/col (lane&31), k = (lane>>5)*8 + j.
//  C/D: col = lane&31, row = (reg&3) + 8*(reg>>2) + 4*(lane>>5).
__global__ __launch_bounds__(256, 2) void fused_mlp(
        const __hip_bfloat16* __restrict__ fab2,
        const __hip_bfloat16* __restrict__ w1t,
        const float* __restrict__ b1,
        const float* __restrict__ W2,
        const float* __restrict__ b2,
        const float* __restrict__ f_t,
        float* __restrict__ out) {
    __shared__ __align__(16) float partial[16][4][64];   // 16 KB, no dbuf

    const int bid = blockIdx.x;
    const int m     = bid & 127;     // same-m blocks 128 apart -> same XCD L2
    const int slice = bid >> 7;      // 0..3, 1024 rows each
    const int row_base = slice * 1024;
    const int t = threadIdx.x;
    const int w = t >> 6;            // wave = hid col group 0..3 (64 cols)
    const int lane = t & 63;
    const int l31 = lane & 31;
    const int h = lane >> 5;         // 0..1 (k-half / row-half selector)

    // ---- prologue: W1T frags (MFMA A operand): hid = l31 (+32*hi2),
    // k = ks*16 + h*8 .. +8  -> b128 loads from w1t.
    bf16x8 bfrag[2][9];
#pragma unroll
    for (int hi2 = 0; hi2 < 2; ++hi2) {
        const int col = w * 64 + hi2 * 32 + l31;
        const __hip_bfloat16* wp = w1t + ((size_t)m * HID + col) * KP + h * 8;
#pragma unroll
        for (int ks = 0; ks < 9; ++ks)
            bfrag[hi2][ks] = *(const bf16x8*)(wp + ks * 16);
    }
    // w2v/b1v [hi2][reg]: reg = q*4+i -> hid row 8q + 4h + i
    f32x16 w2v[2], b1v[2];
#pragma unroll
    for (int hi2 = 0; hi2 < 2; ++hi2) {
        const float* wp2 = W2 + (size_t)m * HID + w * 64 + hi2 * 32 + 4 * h;
        const float* bp1 = b1 + (size_t)m * HID + w * 64 + hi2 * 32 + 4 * h;
#pragma unroll
        for (int q = 0; q < 4; ++q) {
            f32x4 v = *(const f32x4*)(wp2 + 8 * q);
            f32x4 bv = *(const f32x4*)(bp1 + 8 * q);
#pragma unroll
            for (int i = 0; i < 4; ++i) {
                w2v[hi2][q * 4 + i] = v[i];
                b1v[hi2][q * 4 + i] = bv[i];
            }
        }
    }
    const float b2v = b2[m];

    for (int tile = 0; tile < 16; ++tile) {
        const int r0 = row_base + tile * 64;
        // per-lane A bases: chunk (ks*2+h) plane, rows r0 + bj2*32 + l31
        const __hip_bfloat16* fb0 = fab2 + ((size_t)h * BATCH + r0 + l31) * 8;
        const __hip_bfloat16* fb1 = fb0 + 32 * 8;

        f32x16 acc[2][2];   // [hi2][bj2]

        // ks = 0: C = b1 fragment (bias folded; no acc zero-init VALU)
        {
            bf16x8 a0 = *(const bf16x8*)fb0;
            bf16x8 a1 = *(const bf16x8*)fb1;
#pragma unroll
            for (int hi2 = 0; hi2 < 2; ++hi2) {
                acc[hi2][0] = __builtin_amdgcn_mfma_f32_32x32x16_bf16(
                    bfrag[hi2][0], a0, b1v[hi2], 0, 0, 0);
                acc[hi2][1] = __builtin_amdgcn_mfma_f32_32x32x16_bf16(
                    bfrag[hi2][0], a1, b1v[hi2], 0, 0, 0);
            }
        }
#pragma unroll
        for (int ks = 1; ks < 9; ++ks) {
            bf16x8 a0 = *(const bf16x8*)(fb0 + (size_t)ks * 2 * BATCH * 8);
            bf16x8 a1 = *(const bf16x8*)(fb1 + (size_t)ks * 2 * BATCH * 8);
#pragma unroll
            for (int hi2 = 0; hi2 < 2; ++hi2) {
                acc[hi2][0] = __builtin_amdgcn_mfma_f32_32x32x16_bf16(
                    bfrag[hi2][ks], a0, acc[hi2][0], 0, 0, 0);
                acc[hi2][1] = __builtin_amdgcn_mfma_f32_32x32x16_bf16(
                    bfrag[hi2][ks], a1, acc[hi2][1], 0, 0, 0);
            }
        }

        // ---- epilogue: relu(acc) * W2 (b1 already in acc) -> partial, no sync
        float sarr[2];
#pragma unroll
        for (int bj2 = 0; bj2 < 2; ++bj2) {
            float sr0 = 0.f, sr1 = 0.f, sr2 = 0.f, sr3 = 0.f;
#pragma unroll
            for (int hi2 = 0; hi2 < 2; ++hi2)
#pragma unroll
                for (int q = 0; q < 4; ++q) {
                    float h0 = acc[hi2][bj2][q*4+0]; h0 = h0 > 0.f ? h0 : 0.f;
                    float h1 = acc[hi2][bj2][q*4+1]; h1 = h1 > 0.f ? h1 : 0.f;
                    float h2 = acc[hi2][bj2][q*4+2]; h2 = h2 > 0.f ? h2 : 0.f;
                    float h3 = acc[hi2][bj2][q*4+3]; h3 = h3 > 0.f ? h3 : 0.f;
                    sr0 = fmaf(h0, w2v[hi2][q*4+0], sr0);
                    sr1 = fmaf(h1, w2v[hi2][q*4+1], sr1);
                    sr2 = fmaf(h2, w2v[hi2][q*4+2], sr2);
                    sr3 = fmaf(h3, w2v[hi2][q*4+3], sr3);
                }
            float s = (sr0 + sr1) + (sr2 + sr3);
            // lanes l and l+32 hold complementary hid rows of the same batch col
            s += __shfl_xor(s, 32, 64);
            sarr[bj2] = s;
        }
        if (h == 0) {
            partial[tile][w][l31]      = sarr[0];
            partial[tile][w][32 + l31] = sarr[1];
        }
    }

    // ---- single barrier, then combine all 16 tiles (1024 outputs/block)
    __syncthreads();
#pragma unroll
    for (int i = 0; i < 4; ++i) {
        int idx = i * 256 + t;             // 0..1023
        int tl = idx >> 6;
        int r  = idx & 63;
        int row = row_base + tl * 64 + r;
        float v = (partial[tl][0][r] + partial[tl][1][r])
                + (partial[tl][2][r] + partial[tl][3][r])
                + b2v + f_t[(size_t)row * NF + m];
        out[(size_t)row * NF + m] = v;
    }
}

// ---------------------------------------------------------------------------
extern "C" void kernel_launch(void* const* d_in, const int* in_sizes, int n_in,
                              void* d_out, int out_size, void* d_ws, size_t ws_size,
                              hipStream_t stream) {
    const float* f_t = (const float*)d_in[0];
    const float* a_t = (const float*)d_in[1];
    const float* W1  = (const float*)d_in[2];
    const float* b1  = (const float*)d_in[3];
    const float* W2  = (const float*)d_in[4];
    const float* b2  = (const float*)d_in[5];
    float* out = (float*)d_out;

    // ws layout: w1t bf16 [128][256][144] (9.44 MB),
    //            fab2 bf16 [18][4096][8] k-chunk-major (1.18 MB)
    __hip_bfloat16* w1t  = (__hip_bfloat16*)d_ws;
    __hip_bfloat16* fab2 = (__hip_bfloat16*)((char*)d_ws + (size_t)NF * HID * KP * 2);

    // converts merged: 1152 w1t blocks + 288 fab2 blocks
    hipLaunchKernelGGL(convert_all, dim3(1440), dim3(256), 0, stream,
                       W1, f_t, a_t, w1t, fab2);
    hipLaunchKernelGGL(fused_mlp, dim3(512), dim3(256), 0, stream,
                       fab2, w1t, b1, W2, b2, f_t, out);
}

// Round 15
// 57.189 us; speedup vs baseline: 1.0443x; 1.0443x over previous
//
#include <hip/hip_runtime.h>
#include <hip/hip_bf16.h>

// Problem constants
#define BATCH   4096
#define NF      128    // n features == n models
#define NA      16
#define IN_DIM  144    // K = 144 exactly (9 MFMA k-steps of 16; 18 8-elem chunks)
#define KP      144    // w1t K (b1 folded via MFMA C-operand)
#define HID     256

typedef __attribute__((ext_vector_type(8))) short bf16x8;
typedef __attribute__((ext_vector_type(4))) float f32x4;
typedef __attribute__((ext_vector_type(16))) float f32x16;

// ---------------------------------------------------------------------------
// Merged convert kernel:
//   blocks [0, 1152):      W1 [128][144][256] fp32 -> w1t [128][256][144] bf16
//                          (transposed; b1 folded later via MFMA C-operand)
//   blocks [1152, 1440):   fa -> fab2 bf16, K-CHUNK-MAJOR [18][4096][8]:
//                          plane kc holds k = kc*8..kc*8+8 for all rows ->
//                          a half-wave's frag load is 512 B contiguous.
__global__ void convert_all(const float* __restrict__ W1,
                            const float* __restrict__ f_t,
                            const float* __restrict__ a_t,
                            __hip_bfloat16* __restrict__ w1t,
                            __hip_bfloat16* __restrict__ fab2) {
    const int bid = blockIdx.x;
    const int t = threadIdx.x;
    if (bid < 1152) {
        __shared__ float tile[16][HID];
        int m = bid / 9;
        int kc = bid - m * 9;
        int k0 = kc * 16;
#pragma unroll
        for (int i = 0; i < 16; ++i)
            tile[i][t] = W1[((size_t)m * IN_DIM + (k0 + i)) * HID + t];
        __syncthreads();
        union { ushort us[16]; uint4 q[2]; } pk;
#pragma unroll
        for (int i = 0; i < 16; ++i) {
            __hip_bfloat16 h = __float2bfloat16(tile[i][t]);
            pk.us[i] = *(ushort*)&h;
        }
        uint4* dst = (uint4*)(w1t + ((size_t)m * HID + t) * KP + k0);
        dst[0] = pk.q[0];
        dst[1] = pk.q[1];
    } else {
        int b2i = bid - 1152;          // 0..287
        int cc = b2i / 16;             // k-chunk 0..17
        int rb = b2i - cc * 16;        // row block 0..15
        int row = rb * 256 + t;
        union { ushort us[8]; uint4 q; } pk;
        const float* src = (cc < 16) ? (f_t + (size_t)row * NF + cc * 8)
                                     : (a_t + (size_t)row * NA + (cc - 16) * 8);
#pragma unroll
        for (int j = 0; j < 8; ++j) {
            __hip_bfloat16 h = __float2bfloat16(src[j]);
            pk.us[j] = *(ushort*)&h;
        }
        *(uint4*)(fab2 + ((size_t)cc * BATCH + row) * 8) = pk.q;   // coalesced
    }
}

// ---------------------------------------------------------------------------
// Fused grouped MLP — barrier-free main loop + 2-deep REGISTER PREFETCH.
// Grid 512 = 128 m (bid&127) x 4 slices of 1024 rows; 32 tiles of 32 rows.
// 256 thr = 4 waves; wave w owns hid cols [w*64, w*64+64) = 2 x 32-tiles.
// B (W1T[m]) in registers. A-frags for tile t+1 are loaded into the ping-pong
// buffer (named bufA/bufB, all compile-time indices) BEFORE tile t's MFMAs ->
// compiler emits counted vmcnt waits; ~370 cyc of compute hides the L1/L2
// latency that made R14 latency-bound. Zero barriers in the loop; per-tile
// results go to partial[32][4][32] (no sync), combined after ONE barrier.
// mfma(A=w1t frag, B=fa frag): D[row=hid][col=batch].
//  A/B frag (32x32x16): lane holds row/col (lane&31), k = (lane>>5)*8 + j.
//  C/D: col = lane&31, row = (reg&3) + 8*(reg>>2) + 4*(lane>>5).
__global__ __launch_bounds__(256, 2) void fused_mlp(
        const __hip_bfloat16* __restrict__ fab2,
        const __hip_bfloat16* __restrict__ w1t,
        const float* __restrict__ b1,
        const float* __restrict__ W2,
        const float* __restrict__ b2,
        const float* __restrict__ f_t,
        float* __restrict__ out) {
    __shared__ __align__(16) float partial[32][4][32];   // 16 KB

    const int bid = blockIdx.x;
    const int m     = bid & 127;     // same-m blocks 128 apart -> same XCD L2
    const int slice = bid >> 7;      // 0..3, 1024 rows each
    const int row_base = slice * 1024;
    const int t = threadIdx.x;
    const int w = t >> 6;            // wave = hid col group 0..3 (64 cols)
    const int lane = t & 63;
    const int l31 = lane & 31;
    const int h = lane >> 5;         // 0..1 (k-half / hid-row-half selector)

    // ---- prologue: W1T frags (MFMA A operand): hid = l31 (+32*hi2),
    // k = ks*16 + h*8 .. +8  -> b128 loads from w1t.
    bf16x8 bfrag[2][9];
#pragma unroll
    for (int hi2 = 0; hi2 < 2; ++hi2) {
        const int col = w * 64 + hi2 * 32 + l31;
        const __hip_bfloat16* wp = w1t + ((size_t)m * HID + col) * KP + h * 8;
#pragma unroll
        for (int ks = 0; ks < 9; ++ks)
            bfrag[hi2][ks] = *(const bf16x8*)(wp + ks * 16);
    }
    // w2v/b1v [hi2][reg]: reg = q*4+i -> hid row 8q + 4h + i
    f32x16 w2v[2], b1v[2];
#pragma unroll
    for (int hi2 = 0; hi2 < 2; ++hi2) {
        const float* wp2 = W2 + (size_t)m * HID + w * 64 + hi2 * 32 + 4 * h;
        const float* bp1 = b1 + (size_t)m * HID + w * 64 + hi2 * 32 + 4 * h;
#pragma unroll
        for (int q = 0; q < 4; ++q) {
            f32x4 v = *(const f32x4*)(wp2 + 8 * q);
            f32x4 bv = *(const f32x4*)(bp1 + 8 * q);
#pragma unroll
            for (int i = 0; i < 4; ++i) {
                w2v[hi2][q * 4 + i] = v[i];
                b1v[hi2][q * 4 + i] = bv[i];
            }
        }
    }
    const float b2v = b2[m];

    // per-lane A base: plane h, row column l31
    const __hip_bfloat16* fbase = fab2 + ((size_t)h * BATCH + l31) * 8;

    // load tile RR's 9 chunks into BUF (compile-time ks indices -> registers)
#define LOADT(BUF, RR)                                                        \
    {                                                                         \
        const __hip_bfloat16* fb = fbase + (size_t)(RR) * 8;                  \
        _Pragma("unroll")                                                     \
        for (int ks = 0; ks < 9; ++ks)                                        \
            BUF[ks] = *(const bf16x8*)(fb + (size_t)ks * 2 * BATCH * 8);      \
    }

    // compute one 32-row tile TL from BUF, write partial (no sync)
#define COMPT(BUF, TL)                                                        \
    {                                                                         \
        f32x16 acc[2];                                                        \
        _Pragma("unroll")                                                     \
        for (int hi2 = 0; hi2 < 2; ++hi2)                                     \
            acc[hi2] = __builtin_amdgcn_mfma_f32_32x32x16_bf16(               \
                bfrag[hi2][0], BUF[0], b1v[hi2], 0, 0, 0);                    \
        _Pragma("unroll")                                                     \
        for (int ks = 1; ks < 9; ++ks)                                        \
            _Pragma("unroll")                                                 \
            for (int hi2 = 0; hi2 < 2; ++hi2)                                 \
                acc[hi2] = __builtin_amdgcn_mfma_f32_32x32x16_bf16(           \
                    bfrag[hi2][ks], BUF[ks], acc[hi2], 0, 0, 0);              \
        float sr0 = 0.f, sr1 = 0.f, sr2 = 0.f, sr3 = 0.f;                     \
        _Pragma("unroll")                                                     \
        for (int hi2 = 0; hi2 < 2; ++hi2)                                     \
            _Pragma("unroll")                                                 \
            for (int q = 0; q < 4; ++q) {                                     \
                float h0 = acc[hi2][q*4+0]; h0 = h0 > 0.f ? h0 : 0.f;         \
                float h1 = acc[hi2][q*4+1]; h1 = h1 > 0.f ? h1 : 0.f;         \
                float h2 = acc[hi2][q*4+2]; h2 = h2 > 0.f ? h2 : 0.f;         \
                float h3 = acc[hi2][q*4+3]; h3 = h3 > 0.f ? h3 : 0.f;         \
                sr0 = fmaf(h0, w2v[hi2][q*4+0], sr0);                         \
                sr1 = fmaf(h1, w2v[hi2][q*4+1], sr1);                         \
                sr2 = fmaf(h2, w2v[hi2][q*4+2], sr2);                         \
                sr3 = fmaf(h3, w2v[hi2][q*4+3], sr3);                         \
            }                                                                 \
        float s = (sr0 + sr1) + (sr2 + sr3);                                  \
        s += __shfl_xor(s, 32, 64);                                           \
        if (h == 0) partial[TL][w][l31] = s;                                  \
    }

    bf16x8 bufA[9], bufB[9];
    LOADT(bufA, row_base);
#pragma unroll 4
    for (int tp = 0; tp < 16; ++tp) {
        const int t0 = 2 * tp;
        LOADT(bufB, row_base + (t0 + 1) * 32);       // prefetch odd tile
        COMPT(bufA, t0);
        if (t0 + 2 < 32) LOADT(bufA, row_base + (t0 + 2) * 32);  // prefetch next even
        COMPT(bufB, t0 + 1);
    }
#undef LOADT
#undef COMPT

    // ---- single barrier, then combine all 32 tiles (1024 outputs/block)
    __syncthreads();
#pragma unroll
    for (int i = 0; i < 4; ++i) {
        int idx = i * 256 + t;             // 0..1023
        int tl = idx >> 5;
        int r  = idx & 31;
        int row = row_base + tl * 32 + r;
        float v = (partial[tl][0][r] + partial[tl][1][r])
                + (partial[tl][2][r] + partial[tl][3][r])
                + b2v + f_t[(size_t)row * NF + m];
        out[(size_t)row * NF + m] = v;
    }
}

// ---------------------------------------------------------------------------
extern "C" void kernel_launch(void* const* d_in, const int* in_sizes, int n_in,
                              void* d_out, int out_size, void* d_ws, size_t ws_size,
                              hipStream_t stream) {
    const float* f_t = (const float*)d_in[0];
    const float* a_t = (const float*)d_in[1];
    const float* W1  = (const float*)d_in[2];
    const float* b1  = (const float*)d_in[3];
    const float* W2  = (const float*)d_in[4];
    const float* b2  = (const float*)d_in[5];
    float* out = (float*)d_out;

    // ws layout: w1t bf16 [128][256][144] (9.44 MB),
    //            fab2 bf16 [18][4096][8] k-chunk-major (1.18 MB)
    __hip_bfloat16* w1t  = (__hip_bfloat16*)d_ws;
    __hip_bfloat16* fab2 = (__hip_bfloat16*)((char*)d_ws + (size_t)NF * HID * KP * 2);

    // converts merged: 1152 w1t blocks + 288 fab2 blocks
    hipLaunchKernelGGL(convert_all, dim3(1440), dim3(256), 0, stream,
                       W1, f_t, a_t, w1t, fab2);
    hipLaunchKernelGGL(fused_mlp, dim3(512), dim3(256), 0, stream,
                       fab2, w1t, b1, W2, b2, f_t, out);
}